// Round 1
// baseline (369.310 us; speedup 1.0000x reference)
//
#include <hip/hip_runtime.h>
#include <hip/hip_bf16.h>

namespace {

constexpr int BB = 8;
constexpr int NPTS = 2048;
constexpr int CC = 128;
constexpr int MM = BB * NPTS;   // 16384
constexpr int OO = 256;
constexpr int K1 = 160;         // 131 padded to multiple of 32
constexpr int KNNK = 16;

typedef __attribute__((ext_vector_type(8))) short bf16x8;
typedef __attribute__((ext_vector_type(4))) float f32x4;

__device__ __forceinline__ unsigned short f2bf(float v) {
  unsigned u = __builtin_bit_cast(unsigned, v);
  u += 0x7FFFu + ((u >> 16) & 1u);
  return (unsigned short)(u >> 16);
}

__global__ void zero_stats(double* p) {
  int i = threadIdx.x;
  if (i < 1024) p[i] = 0.0;
}

// W1 [131][256] f32 -> W1T bf16 [256][160] (zero-padded k>=131)
// W2 [256][256] f32 -> W2T bf16 [256][256]
__global__ void prep_weights(const float* __restrict__ W1, const float* __restrict__ W2,
                             unsigned short* __restrict__ W1T, unsigned short* __restrict__ W2T) {
  int i = blockIdx.x * 256 + threadIdx.x;
  if (i < 256 * K1) {
    int n = i / K1, k = i % K1;
    float v = (k < 131) ? W1[k * 256 + n] : 0.f;
    W1T[i] = f2bf(v);
  } else {
    int j = i - 256 * K1;
    if (j < 256 * 256) {
      int n = j / 256, k = j % 256;
      W2T[j] = f2bf(W2[k * 256 + n]);
    }
  }
}

// 16-NN per point. 4 threads per query (j strided by 4), LDS merge of 4 sorted lists.
__global__ __launch_bounds__(256) void knn_kernel(const float* __restrict__ pos,
                                                  int* __restrict__ nn_idx) {
#pragma clang fp contract(off)
  __shared__ float px[NPTS], py[NPTS], pz[NPTS];
  __shared__ float md[64][4][16];
  __shared__ int   mi[64][4][16];
  const int b = blockIdx.y;
  const int tid = threadIdx.x;
  const float* pb = pos + (size_t)b * NPTS * 3;
  for (int i = tid; i < NPTS; i += 256) {
    px[i] = pb[3 * i];
    py[i] = pb[3 * i + 1];
    pz[i] = pb[3 * i + 2];
  }
  __syncthreads();
  const int ql = tid >> 2;                 // 0..63 local query
  const int s  = tid & 3;                  // sub-thread
  const int q  = (blockIdx.x << 6) + ql;   // query in batch
  const float qx = px[q], qy = py[q], qz = pz[q];
  float bd[16]; int bi[16];
#pragma unroll
  for (int k = 0; k < 16; ++k) { bd[k] = 3.4e38f; bi[k] = 0; }
  for (int i = 0; i < 512; ++i) {
    const int j = (i << 2) + s;            // interleaved: 4 distinct banks per wave
    float dx = qx - px[j];
    float dy = qy - py[j];
    float dz = qz - pz[j];
    float d = ((dx * dx) + (dy * dy)) + (dz * dz);  // numpy order, no fma
    if (d < bd[15]) {
      bd[15] = d; bi[15] = j;
#pragma unroll
      for (int k = 15; k > 0; --k) {
        if (bd[k] < bd[k - 1]) {
          float td = bd[k]; bd[k] = bd[k - 1]; bd[k - 1] = td;
          int   ti = bi[k]; bi[k] = bi[k - 1]; bi[k - 1] = ti;
        }
      }
    }
  }
#pragma unroll
  for (int k = 0; k < 16; ++k) { md[ql][s][k] = bd[k]; mi[ql][s][k] = bi[k]; }
  __syncthreads();
  if (tid < 64) {
    int p0 = 0, p1 = 0, p2 = 0, p3 = 0;
    int* out = nn_idx + ((size_t)(b * NPTS + (blockIdx.x << 6) + tid)) * KNNK;
    for (int o = 0; o < 16; ++o) {
      float d0 = md[tid][0][p0], d1 = md[tid][1][p1], d2 = md[tid][2][p2], d3 = md[tid][3][p3];
      int   i0 = mi[tid][0][p0], i1 = mi[tid][1][p1], i2 = mi[tid][2][p2], i3 = mi[tid][3][p3];
      float bdv = d0; int bix = i0; int bl = 0;
      if (d1 < bdv || (d1 == bdv && i1 < bix)) { bdv = d1; bix = i1; bl = 1; }
      if (d2 < bdv || (d2 == bdv && i2 < bix)) { bdv = d2; bix = i2; bl = 2; }
      if (d3 < bdv || (d3 == bdv && i3 < bix)) { bdv = d3; bix = i3; bl = 3; }
      out[o] = bix;
      if (bl == 0) ++p0; else if (bl == 1) ++p1; else if (bl == 2) ++p2; else ++p3;
    }
  }
}

// avg[p][0:128] = mean_k x[b, idx[k], c]; [128:131] = mean pos; [131:160]=0  (bf16)
__global__ __launch_bounds__(128) void gather_avg(const float* __restrict__ x,
                                                  const float* __restrict__ pos,
                                                  const int* __restrict__ nn_idx,
                                                  unsigned short* __restrict__ avg) {
  __shared__ int sidx[16];
  const int p = blockIdx.x;
  const int b = p >> 11;
  const int tid = threadIdx.x;
  if (tid < 16) sidx[tid] = nn_idx[(size_t)p * KNNK + tid];
  __syncthreads();
  const float* xb = x + (size_t)b * NPTS * CC;
  float sacc = 0.f;
#pragma unroll
  for (int k = 0; k < 16; ++k) sacc += xb[(size_t)sidx[k] * CC + tid];
  avg[(size_t)p * K1 + tid] = f2bf(sacc * 0.0625f);
  if (tid < 32) {
    float v = 0.f;
    if (tid < 3) {
      const float* pb = pos + (size_t)b * NPTS * 3;
#pragma unroll
      for (int k = 0; k < 16; ++k) v += pb[sidx[k] * 3 + tid];
      v *= 0.0625f;
    }
    avg[(size_t)p * K1 + 128 + tid] = f2bf(v);
  }
}

// C[M][256] = A[M][Kp] @ B[Kp][256] + bias, A bf16 row-major, BT bf16 [256][Kp]
__global__ __launch_bounds__(256) void gemm_bf16(const unsigned short* __restrict__ A,
                                                 const unsigned short* __restrict__ BT,
                                                 const float* __restrict__ bias,
                                                 float* __restrict__ Cmat, int Kp) {
  __shared__ __align__(16) unsigned short As[64][56];
  __shared__ __align__(16) unsigned short Bs[64][56];
  const int tid = threadIdx.x;
  const int m0 = blockIdx.x * 64;
  const int n0 = blockIdx.y * 64;
  const int w = tid >> 6, lane = tid & 63;
  const int wr = w >> 1, wc = w & 1;
  const int l15 = lane & 15;
  const int kk = (lane >> 4) * 8;
  f32x4 acc[2][2] = {};
  const int sr = tid >> 2;
  const int sk = (tid & 3) * 8;
  const unsigned short* Aptr = A + (size_t)(m0 + sr) * Kp + sk;
  const unsigned short* Bptr = BT + (size_t)(n0 + sr) * Kp + sk;
  for (int k0 = 0; k0 < Kp; k0 += 32) {
    *(int4*)(&As[sr][sk]) = *(const int4*)(Aptr + k0);
    *(int4*)(&Bs[sr][sk]) = *(const int4*)(Bptr + k0);
    __syncthreads();
    bf16x8 a0  = *(const bf16x8*)(&As[wr * 32 + l15][kk]);
    bf16x8 a1  = *(const bf16x8*)(&As[wr * 32 + 16 + l15][kk]);
    bf16x8 b0  = *(const bf16x8*)(&Bs[wc * 32 + l15][kk]);
    bf16x8 b1v = *(const bf16x8*)(&Bs[wc * 32 + 16 + l15][kk]);
    acc[0][0] = __builtin_amdgcn_mfma_f32_16x16x32_bf16(a0, b0,  acc[0][0], 0, 0, 0);
    acc[0][1] = __builtin_amdgcn_mfma_f32_16x16x32_bf16(a0, b1v, acc[0][1], 0, 0, 0);
    acc[1][0] = __builtin_amdgcn_mfma_f32_16x16x32_bf16(a1, b0,  acc[1][0], 0, 0, 0);
    acc[1][1] = __builtin_amdgcn_mfma_f32_16x16x32_bf16(a1, b1v, acc[1][1], 0, 0, 0);
    __syncthreads();
  }
#pragma unroll
  for (int fr = 0; fr < 2; ++fr)
#pragma unroll
    for (int fc = 0; fc < 2; ++fc) {
      int col = n0 + wc * 32 + fc * 16 + l15;
      float bv = bias[col];
#pragma unroll
      for (int r = 0; r < 4; ++r) {
        int row = m0 + wr * 32 + fr * 16 + (lane >> 4) * 4 + r;
        Cmat[(size_t)row * OO + col] = acc[fr][fc][r] + bv;
      }
    }
}

// per-channel sum/sumsq over rows, double atomics
__global__ __launch_bounds__(256) void col_stats(const float* __restrict__ X,
                                                 double* __restrict__ dsum,
                                                 double* __restrict__ dsumsq) {
  const int c = threadIdx.x;
  const int r0 = blockIdx.x * 128;
  float s = 0.f, s2 = 0.f;
  for (int r = 0; r < 128; ++r) {
    float v = X[(size_t)(r0 + r) * OO + c];
    s += v;
    s2 = fmaf(v, v, s2);
  }
  atomicAdd(&dsum[c], (double)s);
  atomicAdd(&dsumsq[c], (double)s2);
}

__global__ void finalize_stats(const double* __restrict__ dsum, const double* __restrict__ dsumsq,
                               const float* __restrict__ gamma, const float* __restrict__ beta,
                               float* __restrict__ scale, float* __restrict__ shift) {
  int c = threadIdx.x;
  double mu = dsum[c] * (1.0 / 16384.0);
  double var = dsumsq[c] * (1.0 / 16384.0) - mu * mu;
  float sc = (float)((double)gamma[c] / sqrt(var + 1e-5));
  float sh = beta[c] - (float)mu * sc;
  scale[c] = sc;
  shift[c] = sh;
}

__global__ __launch_bounds__(256) void bn_relu_bf16(const float* __restrict__ pre,
                                                    const float* __restrict__ scale,
                                                    const float* __restrict__ shift,
                                                    unsigned short* __restrict__ h) {
  int i = (blockIdx.x * 256 + threadIdx.x) * 4;
  float4 v = *(const float4*)(pre + i);
  int c = i & 255;
  float4 sc = *(const float4*)(scale + c);
  float4 sh = *(const float4*)(shift + c);
  ushort4 o;
  o.x = f2bf(fmaxf(fmaf(v.x, sc.x, sh.x), 0.f));
  o.y = f2bf(fmaxf(fmaf(v.y, sc.y, sh.y), 0.f));
  o.z = f2bf(fmaxf(fmaf(v.z, sc.z, sh.z), 0.f));
  o.w = f2bf(fmaxf(fmaf(v.w, sc.w, sh.w), 0.f));
  *(ushort4*)(h + i) = o;
}

__global__ __launch_bounds__(256) void bn_out(float* __restrict__ pre,
                                              const float* __restrict__ scale,
                                              const float* __restrict__ shift) {
  int i = (blockIdx.x * 256 + threadIdx.x) * 4;
  float4 v = *(const float4*)(pre + i);
  int c = i & 255;
  float4 sc = *(const float4*)(scale + c);
  float4 sh = *(const float4*)(shift + c);
  float4 o;
  o.x = fmaf(v.x, sc.x, sh.x);
  o.y = fmaf(v.y, sc.y, sh.y);
  o.z = fmaf(v.z, sc.z, sh.z);
  o.w = fmaf(v.w, sc.w, sh.w);
  *(float4*)(pre + i) = o;
}

}  // namespace

extern "C" void kernel_launch(void* const* d_in, const int* in_sizes, int n_in,
                              void* d_out, int out_size, void* d_ws, size_t ws_size,
                              hipStream_t stream) {
  const float* x   = (const float*)d_in[0];
  const float* pos = (const float*)d_in[1];
  const float* W1  = (const float*)d_in[2];
  const float* b1  = (const float*)d_in[3];
  const float* g1  = (const float*)d_in[4];
  const float* be1 = (const float*)d_in[5];
  const float* W2  = (const float*)d_in[6];
  const float* b2  = (const float*)d_in[7];
  const float* g2  = (const float*)d_in[8];
  const float* be2 = (const float*)d_in[9];

  char* ws = (char*)d_ws;
  double* stats          = (double*)(ws + 0);          // 1024 doubles: sum1,sq1,sum2,sq2
  float* scale1          = (float*)(ws + 8192);
  float* shift1          = scale1 + 256;
  float* scale2          = shift1 + 256;
  float* shift2          = scale2 + 256;
  int* nn_idx            = (int*)(ws + 12288);         // 16384*16 int
  unsigned short* avg    = (unsigned short*)(ws + 1060864);   // 16384*160 bf16
  unsigned short* W1T    = (unsigned short*)(ws + 6303744);   // 256*160 bf16
  unsigned short* W2T    = (unsigned short*)(ws + 6385664);   // 256*256 bf16
  float* pre1            = (float*)(ws + 6516736);            // 16384*256 f32
  unsigned short* hbuf   = (unsigned short*)(ws + 23293952);  // 16384*256 bf16
  float* pre2            = (float*)d_out;                     // reuse output buffer

  zero_stats<<<1, 1024, 0, stream>>>(stats);
  prep_weights<<<416, 256, 0, stream>>>(W1, W2, W1T, W2T);
  knn_kernel<<<dim3(NPTS / 64, BB), 256, 0, stream>>>(pos, nn_idx);
  gather_avg<<<MM, 128, 0, stream>>>(x, pos, nn_idx, avg);
  gemm_bf16<<<dim3(MM / 64, OO / 64), 256, 0, stream>>>(avg, W1T, b1, pre1, K1);
  col_stats<<<128, 256, 0, stream>>>(pre1, stats, stats + 256);
  finalize_stats<<<1, 256, 0, stream>>>(stats, stats + 256, g1, be1, scale1, shift1);
  bn_relu_bf16<<<4096, 256, 0, stream>>>(pre1, scale1, shift1, hbuf);
  gemm_bf16<<<dim3(MM / 64, OO / 64), 256, 0, stream>>>(hbuf, W2T, b2, pre2, OO);
  col_stats<<<128, 256, 0, stream>>>(pre2, stats + 512, stats + 768);
  finalize_stats<<<1, 256, 0, stream>>>(stats + 512, stats + 768, g2, be2, scale2, shift2);
  bn_out<<<4096, 256, 0, stream>>>(pre2, scale2, shift2);
}

// Round 2
// 112.514 us; speedup vs baseline: 3.2823x; 3.2823x over previous
//
#include <hip/hip_runtime.h>
#include <hip/hip_bf16.h>

namespace {

constexpr int BB = 8;
constexpr int NPTS = 2048;
constexpr int CC = 128;
constexpr int MM = BB * NPTS;   // 16384
constexpr int OO = 256;
constexpr int K1 = 160;         // 131 padded to multiple of 32
constexpr int KNNK = 16;

typedef __attribute__((ext_vector_type(8))) short bf16x8;
typedef __attribute__((ext_vector_type(4))) float f32x4;

__device__ __forceinline__ unsigned short f2bf(float v) {
  unsigned u = __builtin_bit_cast(unsigned, v);
  u += 0x7FFFu + ((u >> 16) & 1u);
  return (unsigned short)(u >> 16);
}

__device__ __forceinline__ unsigned long long shflxor64(unsigned long long v, int m) {
  int lo = __shfl_xor((int)(unsigned)v, m, 64);
  int hi = __shfl_xor((int)(unsigned)(v >> 32), m, 64);
  return ((unsigned long long)(unsigned)hi << 32) | (unsigned)lo;
}

__device__ __forceinline__ unsigned long long shfl64(unsigned long long v, int src) {
  int lo = __shfl((int)(unsigned)v, src, 64);
  int hi = __shfl((int)(unsigned)(v >> 32), src, 64);
  return ((unsigned long long)(unsigned)hi << 32) | (unsigned)lo;
}

// Full bitonic sort of 64 keys (one per lane), ascending by lane.
__device__ __forceinline__ unsigned long long bitonic_sort64(unsigned long long key, int lane) {
#pragma unroll
  for (int k = 2; k <= 64; k <<= 1) {
#pragma unroll
    for (int j = k >> 1; j > 0; j >>= 1) {
      unsigned long long other = shflxor64(key, j);
      bool dirAsc = (lane & k) == 0;
      bool lower = (lane & j) == 0;
      bool keepMin = (lower == dirAsc);
      bool less = key < other;
      key = (less == keepMin) ? key : other;
    }
  }
  return key;
}

__global__ void zero_stats(double* p) {
  int i = threadIdx.x;
  if (i < 1024) p[i] = 0.0;
}

// W1 [131][256] f32 -> W1T bf16 [256][160] (zero-padded k>=131)
// W2 [256][256] f32 -> W2T bf16 [256][256]
__global__ void prep_weights(const float* __restrict__ W1, const float* __restrict__ W2,
                             unsigned short* __restrict__ W1T, unsigned short* __restrict__ W2T) {
  int i = blockIdx.x * 256 + threadIdx.x;
  if (i < 256 * K1) {
    int n = i / K1, k = i % K1;
    float v = (k < 131) ? W1[k * 256 + n] : 0.f;
    W1T[i] = f2bf(v);
  } else {
    int j = i - 256 * K1;
    if (j < 256 * 256) {
      int n = j / 256, k = j % 256;
      W2T[j] = f2bf(W2[k * 256 + n]);
    }
  }
}

// Exact 16-NN, one wave per query. Packed key = (f32_dist_bits << 11) | idx is
// unique per candidate -> lexicographic (d, idx) order == jax.lax.top_k ties.
// Pass 1: per-lane min over 32 strided candidates. Tkey = 16th smallest of the
// 64 lane minima (safe upper bound on true 16th key; <= 481 survivors proven).
// Pass 2: ballot-compact survivors to LDS; bitonic-sort; first 16 out.
__global__ __launch_bounds__(256) void knn_kernel(const float* __restrict__ pos,
                                                  int* __restrict__ nn_idx) {
#pragma clang fp contract(off)
  __shared__ float px[NPTS], py[NPTS], pz[NPTS];
  __shared__ unsigned long long sbuf[4][512];
  const int b = blockIdx.y;
  const int tid = threadIdx.x;
  const float* pb = pos + (size_t)b * NPTS * 3;
  for (int i = tid; i < NPTS; i += 256) {
    px[i] = pb[3 * i];
    py[i] = pb[3 * i + 1];
    pz[i] = pb[3 * i + 2];
  }
  __syncthreads();
  const int lane = tid & 63;
  const int wid = tid >> 6;
  const int q = blockIdx.x * 4 + wid;  // query within batch
  const float qx = px[q], qy = py[q], qz = pz[q];

  // Pass 1: per-lane min key over candidates j = lane + 64*t
  unsigned long long mink = ~0ull;
  for (int t = 0; t < 32; ++t) {
    const int j = lane + (t << 6);
    float dx = qx - px[j];
    float dy = qy - py[j];
    float dz = qz - pz[j];
    float d = ((dx * dx) + (dy * dy)) + (dz * dz);  // reference order, no fma
    unsigned long long key = ((unsigned long long)__float_as_uint(d) << 11) | (unsigned)j;
    mink = (key < mink) ? key : mink;
  }
  unsigned long long skey = bitonic_sort64(mink, lane);
  const unsigned long long Tkey = shfl64(skey, 15);

  // Pass 2: compact survivors (key <= Tkey) into per-wave LDS buffer
  unsigned long long* buf = sbuf[wid];
  int base = 0;
  for (int t = 0; t < 32; ++t) {
    const int j = lane + (t << 6);
    float dx = qx - px[j];
    float dy = qy - py[j];
    float dz = qz - pz[j];
    float d = ((dx * dx) + (dy * dy)) + (dz * dz);
    unsigned long long key = ((unsigned long long)__float_as_uint(d) << 11) | (unsigned)j;
    bool surv = key <= Tkey;
    unsigned long long mask = __ballot(surv);
    if (surv) {
      int off = __popcll(mask & ((1ull << lane) - 1ull));
      buf[base + off] = key;
    }
    base += (int)__popcll(mask);
  }

  int* out = nn_idx + ((size_t)b * NPTS + q) * KNNK;
  if (base <= 64) {
    unsigned long long key = (lane < base) ? buf[lane] : ~0ull;
    key = bitonic_sort64(key, lane);
    if (lane < 16) out[lane] = (int)(key & 2047ull);
  } else {
    // rare exact fallback: iterative wave-argmin extraction (base <= 481)
    unsigned long long mk[8];
#pragma unroll
    for (int j2 = 0; j2 < 8; ++j2) {
      int t2 = lane + (j2 << 6);
      mk[j2] = (t2 < base) ? buf[t2] : ~0ull;
    }
    for (int o = 0; o < 16; ++o) {
      unsigned long long m = mk[0];
#pragma unroll
      for (int j2 = 1; j2 < 8; ++j2) m = (mk[j2] < m) ? mk[j2] : m;
#pragma unroll
      for (int off = 32; off > 0; off >>= 1) {
        unsigned long long o2 = shflxor64(m, off);
        m = (o2 < m) ? o2 : m;
      }
      if (lane == 0) out[o] = (int)(m & 2047ull);
#pragma unroll
      for (int j2 = 0; j2 < 8; ++j2) mk[j2] = (mk[j2] == m) ? ~0ull : mk[j2];
    }
  }
}

// avg[p][0:128] = mean_k x[b, idx[k], c]; [128:131] = mean pos; [131:160]=0  (bf16)
__global__ __launch_bounds__(128) void gather_avg(const float* __restrict__ x,
                                                  const float* __restrict__ pos,
                                                  const int* __restrict__ nn_idx,
                                                  unsigned short* __restrict__ avg) {
  __shared__ int sidx[16];
  const int p = blockIdx.x;
  const int b = p >> 11;
  const int tid = threadIdx.x;
  if (tid < 16) sidx[tid] = nn_idx[(size_t)p * KNNK + tid];
  __syncthreads();
  const float* xb = x + (size_t)b * NPTS * CC;
  float sacc = 0.f;
#pragma unroll
  for (int k = 0; k < 16; ++k) sacc += xb[(size_t)sidx[k] * CC + tid];
  avg[(size_t)p * K1 + tid] = f2bf(sacc * 0.0625f);
  if (tid < 32) {
    float v = 0.f;
    if (tid < 3) {
      const float* pb = pos + (size_t)b * NPTS * 3;
#pragma unroll
      for (int k = 0; k < 16; ++k) v += pb[sidx[k] * 3 + tid];
      v *= 0.0625f;
    }
    avg[(size_t)p * K1 + 128 + tid] = f2bf(v);
  }
}

// C[M][256] = A[M][Kp] @ B[Kp][256] + bias, A bf16 row-major, BT bf16 [256][Kp]
__global__ __launch_bounds__(256) void gemm_bf16(const unsigned short* __restrict__ A,
                                                 const unsigned short* __restrict__ BT,
                                                 const float* __restrict__ bias,
                                                 float* __restrict__ Cmat, int Kp) {
  __shared__ __align__(16) unsigned short As[64][56];
  __shared__ __align__(16) unsigned short Bs[64][56];
  const int tid = threadIdx.x;
  const int m0 = blockIdx.x * 64;
  const int n0 = blockIdx.y * 64;
  const int w = tid >> 6, lane = tid & 63;
  const int wr = w >> 1, wc = w & 1;
  const int l15 = lane & 15;
  const int kk = (lane >> 4) * 8;
  f32x4 acc[2][2] = {};
  const int sr = tid >> 2;
  const int sk = (tid & 3) * 8;
  const unsigned short* Aptr = A + (size_t)(m0 + sr) * Kp + sk;
  const unsigned short* Bptr = BT + (size_t)(n0 + sr) * Kp + sk;
  for (int k0 = 0; k0 < Kp; k0 += 32) {
    *(int4*)(&As[sr][sk]) = *(const int4*)(Aptr + k0);
    *(int4*)(&Bs[sr][sk]) = *(const int4*)(Bptr + k0);
    __syncthreads();
    bf16x8 a0  = *(const bf16x8*)(&As[wr * 32 + l15][kk]);
    bf16x8 a1  = *(const bf16x8*)(&As[wr * 32 + 16 + l15][kk]);
    bf16x8 b0  = *(const bf16x8*)(&Bs[wc * 32 + l15][kk]);
    bf16x8 b1v = *(const bf16x8*)(&Bs[wc * 32 + 16 + l15][kk]);
    acc[0][0] = __builtin_amdgcn_mfma_f32_16x16x32_bf16(a0, b0,  acc[0][0], 0, 0, 0);
    acc[0][1] = __builtin_amdgcn_mfma_f32_16x16x32_bf16(a0, b1v, acc[0][1], 0, 0, 0);
    acc[1][0] = __builtin_amdgcn_mfma_f32_16x16x32_bf16(a1, b0,  acc[1][0], 0, 0, 0);
    acc[1][1] = __builtin_amdgcn_mfma_f32_16x16x32_bf16(a1, b1v, acc[1][1], 0, 0, 0);
    __syncthreads();
  }
#pragma unroll
  for (int fr = 0; fr < 2; ++fr)
#pragma unroll
    for (int fc = 0; fc < 2; ++fc) {
      int col = n0 + wc * 32 + fc * 16 + l15;
      float bv = bias[col];
#pragma unroll
      for (int r = 0; r < 4; ++r) {
        int row = m0 + wr * 32 + fr * 16 + (lane >> 4) * 4 + r;
        Cmat[(size_t)row * OO + col] = acc[fr][fc][r] + bv;
      }
    }
}

// per-channel sum/sumsq over rows, double atomics
__global__ __launch_bounds__(256) void col_stats(const float* __restrict__ X,
                                                 double* __restrict__ dsum,
                                                 double* __restrict__ dsumsq) {
  const int c = threadIdx.x;
  const int r0 = blockIdx.x * 128;
  float s = 0.f, s2 = 0.f;
  for (int r = 0; r < 128; ++r) {
    float v = X[(size_t)(r0 + r) * OO + c];
    s += v;
    s2 = fmaf(v, v, s2);
  }
  atomicAdd(&dsum[c], (double)s);
  atomicAdd(&dsumsq[c], (double)s2);
}

__global__ void finalize_stats(const double* __restrict__ dsum, const double* __restrict__ dsumsq,
                               const float* __restrict__ gamma, const float* __restrict__ beta,
                               float* __restrict__ scale, float* __restrict__ shift) {
  int c = threadIdx.x;
  double mu = dsum[c] * (1.0 / 16384.0);
  double var = dsumsq[c] * (1.0 / 16384.0) - mu * mu;
  float sc = (float)((double)gamma[c] / sqrt(var + 1e-5));
  float sh = beta[c] - (float)mu * sc;
  scale[c] = sc;
  shift[c] = sh;
}

__global__ __launch_bounds__(256) void bn_relu_bf16(const float* __restrict__ pre,
                                                    const float* __restrict__ scale,
                                                    const float* __restrict__ shift,
                                                    unsigned short* __restrict__ h) {
  int i = (blockIdx.x * 256 + threadIdx.x) * 4;
  float4 v = *(const float4*)(pre + i);
  int c = i & 255;
  float4 sc = *(const float4*)(scale + c);
  float4 sh = *(const float4*)(shift + c);
  ushort4 o;
  o.x = f2bf(fmaxf(fmaf(v.x, sc.x, sh.x), 0.f));
  o.y = f2bf(fmaxf(fmaf(v.y, sc.y, sh.y), 0.f));
  o.z = f2bf(fmaxf(fmaf(v.z, sc.z, sh.z), 0.f));
  o.w = f2bf(fmaxf(fmaf(v.w, sc.w, sh.w), 0.f));
  *(ushort4*)(h + i) = o;
}

__global__ __launch_bounds__(256) void bn_out(float* __restrict__ pre,
                                              const float* __restrict__ scale,
                                              const float* __restrict__ shift) {
  int i = (blockIdx.x * 256 + threadIdx.x) * 4;
  float4 v = *(const float4*)(pre + i);
  int c = i & 255;
  float4 sc = *(const float4*)(scale + c);
  float4 sh = *(const float4*)(shift + c);
  float4 o;
  o.x = fmaf(v.x, sc.x, sh.x);
  o.y = fmaf(v.y, sc.y, sh.y);
  o.z = fmaf(v.z, sc.z, sh.z);
  o.w = fmaf(v.w, sc.w, sh.w);
  *(float4*)(pre + i) = o;
}

}  // namespace

extern "C" void kernel_launch(void* const* d_in, const int* in_sizes, int n_in,
                              void* d_out, int out_size, void* d_ws, size_t ws_size,
                              hipStream_t stream) {
  const float* x   = (const float*)d_in[0];
  const float* pos = (const float*)d_in[1];
  const float* W1  = (const float*)d_in[2];
  const float* b1  = (const float*)d_in[3];
  const float* g1  = (const float*)d_in[4];
  const float* be1 = (const float*)d_in[5];
  const float* W2  = (const float*)d_in[6];
  const float* b2  = (const float*)d_in[7];
  const float* g2  = (const float*)d_in[8];
  const float* be2 = (const float*)d_in[9];

  char* ws = (char*)d_ws;
  double* stats          = (double*)(ws + 0);          // 1024 doubles: sum1,sq1,sum2,sq2
  float* scale1          = (float*)(ws + 8192);
  float* shift1          = scale1 + 256;
  float* scale2          = shift1 + 256;
  float* shift2          = scale2 + 256;
  int* nn_idx            = (int*)(ws + 12288);         // 16384*16 int
  unsigned short* avg    = (unsigned short*)(ws + 1060864);   // 16384*160 bf16
  unsigned short* W1T    = (unsigned short*)(ws + 6303744);   // 256*160 bf16
  unsigned short* W2T    = (unsigned short*)(ws + 6385664);   // 256*256 bf16
  float* pre1            = (float*)(ws + 6516736);            // 16384*256 f32
  unsigned short* hbuf   = (unsigned short*)(ws + 23293952);  // 16384*256 bf16
  float* pre2            = (float*)d_out;                     // reuse output buffer

  zero_stats<<<1, 1024, 0, stream>>>(stats);
  prep_weights<<<416, 256, 0, stream>>>(W1, W2, W1T, W2T);
  knn_kernel<<<dim3(NPTS / 4, BB), 256, 0, stream>>>(pos, nn_idx);
  gather_avg<<<MM, 128, 0, stream>>>(x, pos, nn_idx, avg);
  gemm_bf16<<<dim3(MM / 64, OO / 64), 256, 0, stream>>>(avg, W1T, b1, pre1, K1);
  col_stats<<<128, 256, 0, stream>>>(pre1, stats, stats + 256);
  finalize_stats<<<1, 256, 0, stream>>>(stats, stats + 256, g1, be1, scale1, shift1);
  bn_relu_bf16<<<4096, 256, 0, stream>>>(pre1, scale1, shift1, hbuf);
  gemm_bf16<<<dim3(MM / 64, OO / 64), 256, 0, stream>>>(hbuf, W2T, b2, pre2, OO);
  col_stats<<<128, 256, 0, stream>>>(pre2, stats + 512, stats + 768);
  finalize_stats<<<1, 256, 0, stream>>>(stats + 512, stats + 768, g2, be2, scale2, shift2);
  bn_out<<<4096, 256, 0, stream>>>(pre2, scale2, shift2);
}